// Round 3
// baseline (1710.983 us; speedup 1.0000x reference)
//
#include <hip/hip_runtime.h>

#define STATE 300
#define NCAUSE 40
#define TT 64
#define NP 4
#define SROW 302   // LDS row stride in floats: 8B-aligned, conflict-free for ds_read_b64

// ---------------------------------------------------------------------------
// Kernel 1: fused X_pred (A @ X_prev) and vid_recon (C @ X) per (b,p) block.
// LDS tile TRANSPOSED: Xs[tp][k], tp in [0,64]; tp=0 -> x0, tp>=1 -> X[...,tp-1].
//   X_prev column t == Xs[t][:],  X column t == Xs[t+1][:]
// Weights: wave-uniform rows (readfirstlane) -> s_load into SGPRs.
// X-operand: ds_read_b64 (float2), stride-302 rows = bank-balanced.
// 256 threads = 64 t-lanes x 4 waves; each wave owns 75 A-rows + 64 C-rows.
// ---------------------------------------------------------------------------
__global__ __launch_bounds__(256, 2)
void pred_recon_kernel(const float* __restrict__ X,
                       const float* __restrict__ x0,
                       const float* __restrict__ A,
                       const float* __restrict__ C,
                       float* __restrict__ vid,     // (B,1,32,32,T)
                       float* __restrict__ Xpred) { // (B,4,300,1,T)
    __shared__ __align__(16) float Xs[65 * SROW];   // 78,520 B -> 2 blocks/CU
    const int bp  = blockIdx.x;                     // b*4 + p
    const int tid = threadIdx.x;

    const float* __restrict__ Xbp = X + (size_t)bp * (STATE * TT);

    // ---- stage transposed: Xs[t+1][k] = X[k][t], Xs[0][k] = x0[k] ----------
    for (int idx = tid; idx < STATE * (TT / 4); idx += 256) {
        const int k  = idx >> 4;          // 0..299
        const int t4 = idx & 15;          // 0..15
        const float4 v = ((const float4*)Xbp)[k * (TT / 4) + t4];
        const int tp = t4 * 4 + 1;
        Xs[(tp + 0) * SROW + k] = v.x;
        Xs[(tp + 1) * SROW + k] = v.y;
        Xs[(tp + 2) * SROW + k] = v.z;
        Xs[(tp + 3) * SROW + k] = v.w;
    }
    const float* __restrict__ x0bp = x0 + (size_t)bp * STATE;
    for (int k = tid; k < STATE; k += 256) Xs[k] = x0bp[k];
    __syncthreads();

    const int t   = tid & 63;
    const int wrg = __builtin_amdgcn_readfirstlane(threadIdx.x >> 6); // uniform wave id
    const float2* __restrict__ xA = (const float2*)(Xs + t * SROW);       // X_prev col t
    const float2* __restrict__ xC = (const float2*)(Xs + (t + 1) * SROW); // X col t

    // ---------------- X_pred = A @ X_prev : 75 rows/wave, chunks of 15 ------
    float* __restrict__ outp = Xpred + (size_t)bp * (STATE * TT);
    #pragma unroll 1
    for (int ch = 0; ch < 5; ++ch) {
        const int i0 = wrg * 75 + ch * 15;
        const float* __restrict__ arow = A + (size_t)i0 * STATE;
        float acc[15];
        #pragma unroll
        for (int r = 0; r < 15; ++r) acc[r] = 0.f;

        #pragma unroll 2
        for (int k4 = 0; k4 < STATE / 4; ++k4) {
            const float2 x01 = xA[k4 * 2 + 0];
            const float2 x23 = xA[k4 * 2 + 1];
            #pragma unroll
            for (int r = 0; r < 15; ++r) {
                const float4 w = *(const float4*)(arow + r * STATE + k4 * 4);
                acc[r] += w.x * x01.x + w.y * x01.y + w.z * x23.x + w.w * x23.y;
            }
        }
        #pragma unroll
        for (int r = 0; r < 15; ++r)
            outp[(i0 + r) * TT + t] = acc[r];
    }

    // ---------------- recon = C @ X -> vid (patch_to_image) -----------------
    const int b  = bp >> 2;
    const int p  = bp & 3;
    const int gr = p >> 1;
    const int gc = p & 1;
    float* __restrict__ vb = vid + (size_t)b * (32 * 32 * TT)
                                 + (size_t)(gr * 16) * (32 * TT)
                                 + (size_t)(gc * 16) * TT;
    #pragma unroll 1
    for (int ch = 0; ch < 4; ++ch) {
        const int i0 = wrg * 64 + ch * 16;
        const float* __restrict__ crow = C + (size_t)i0 * STATE;
        float acc[16];
        #pragma unroll
        for (int r = 0; r < 16; ++r) acc[r] = 0.f;

        #pragma unroll 2
        for (int k4 = 0; k4 < STATE / 4; ++k4) {
            const float2 x01 = xC[k4 * 2 + 0];
            const float2 x23 = xC[k4 * 2 + 1];
            #pragma unroll
            for (int r = 0; r < 16; ++r) {
                const float4 w = *(const float4*)(crow + r * STATE + k4 * 4);
                acc[r] += w.x * x01.x + w.y * x01.y + w.z * x23.x + w.w * x23.y;
            }
        }
        #pragma unroll
        for (int r = 0; r < 16; ++r) {
            const int i  = i0 + r;
            const int pr = i >> 4;
            const int pc = i & 15;
            vb[pr * (32 * TT) + pc * TT + t] = acc[r];
        }
    }
}

// ---------------------------------------------------------------------------
// Kernel 2: X_U = 0.1*(1+exp(-Bm@U)) * sum_p |X|.
// Grid (5 s-groups, 256 b): 1280 blocks -> 5 blocks/CU for TLP latency hiding.
// Each block: 60 s-rows; 4 waves x 15 rows; Bm rows via scalar loads.
// ---------------------------------------------------------------------------
__global__ __launch_bounds__(256, 4)
void xu_kernel(const float* __restrict__ X,
               const float* __restrict__ U,
               const float* __restrict__ Bm,
               float* __restrict__ XU) {  // (B,1,300,1,T)
    __shared__ float Us[NCAUSE * 65];    // [k][t] stride 65: conflict-free b32
    const int b   = blockIdx.y;
    const int sg  = blockIdx.x;          // 0..4
    const int tid = threadIdx.x;

    const float* __restrict__ Ub = U + (size_t)b * (NCAUSE * TT);
    for (int idx = tid; idx < NCAUSE * TT; idx += 256) {
        const int k = idx >> 6;
        const int t = idx & 63;
        Us[k * 65 + t] = Ub[idx];
    }
    __syncthreads();

    const int t   = tid & 63;
    const int wrg = __builtin_amdgcn_readfirstlane(threadIdx.x >> 6);
    const int i0  = sg * 60 + wrg * 15;
    const float* __restrict__ brow = Bm + (size_t)i0 * NCAUSE;
    const float* __restrict__ Xb   = X  + (size_t)b * (NP * STATE * TT);
    float* __restrict__ XUb        = XU + (size_t)b * (STATE * TT);

    float bu[15];
    #pragma unroll
    for (int r = 0; r < 15; ++r) bu[r] = 0.f;

    #pragma unroll 2
    for (int k4 = 0; k4 < NCAUSE / 4; ++k4) {
        const float u0 = Us[(k4 * 4 + 0) * 65 + t];
        const float u1 = Us[(k4 * 4 + 1) * 65 + t];
        const float u2 = Us[(k4 * 4 + 2) * 65 + t];
        const float u3 = Us[(k4 * 4 + 3) * 65 + t];
        #pragma unroll
        for (int r = 0; r < 15; ++r) {
            const float4 w = *(const float4*)(brow + r * NCAUSE + k4 * 4);
            bu[r] += w.x * u0 + w.y * u1 + w.z * u2 + w.w * u3;
        }
    }

    #pragma unroll 1
    for (int r = 0; r < 15; ++r) {
        const int s = i0 + r;
        float sab = 0.f;
        #pragma unroll
        for (int p = 0; p < NP; ++p)
            sab += fabsf(Xb[((size_t)p * STATE + s) * TT + t]);
        const float g = 0.1f * (1.f + __expf(-bu[r]));
        XUb[s * TT + t] = g * sab;
    }
}

extern "C" void kernel_launch(void* const* d_in, const int* in_sizes, int n_in,
                              void* d_out, int out_size, void* d_ws, size_t ws_size,
                              hipStream_t stream) {
    const float* X  = (const float*)d_in[0];   // (256,4,300,1,64)
    const float* U  = (const float*)d_in[1];   // (256,1,40,1,64)
    const float* x0 = (const float*)d_in[2];   // (256,4,300,1)
    const float* A  = (const float*)d_in[3];   // (300,300)
    const float* Bm = (const float*)d_in[4];   // (300,40)
    const float* C  = (const float*)d_in[5];   // (256,300)

    float* out   = (float*)d_out;
    float* vid   = out;                         // 256*32*32*64  = 16777216
    float* Xpred = out + 16777216;              // 256*4*300*64  = 19660800
    float* XU    = out + 16777216 + 19660800;   // 256*300*64    =  4915200

    hipLaunchKernelGGL(pred_recon_kernel, dim3(256 * NP), dim3(256), 0, stream,
                       X, x0, A, C, vid, Xpred);
    hipLaunchKernelGGL(xu_kernel, dim3(5, 256), dim3(256), 0, stream,
                       X, U, Bm, XU);
}

// Round 4
// 342.164 us; speedup vs baseline: 5.0005x; 5.0005x over previous
//
#include <hip/hip_runtime.h>

#define STATE  300
#define TDIM   64
#define NCAUSE 40
#define NP     4
#define KPAD   320
#define ROWB   (KPAD*2)        // 640 B per (h,t') LDS row; 640 % 128 == 0 -> XOR swizzle closed
#define LDS_HALF (65*ROWB)     // 41600 B per hi/lo plane
#define NT_A   19
#define NT_C   16
#define WS_NEEDED 716800u      // 2*(19+16)*10*64*8 ushorts * 2B

typedef float f32x4 __attribute__((ext_vector_type(4)));
typedef short s16x8 __attribute__((ext_vector_type(8)));

static __device__ __forceinline__ ushort f2bf(float f) {   // RNE f32 -> bf16 bits
    uint x = __float_as_uint(f);
    x += 0x7fffu + ((x >> 16) & 1u);
    return (ushort)(x >> 16);
}
static __device__ __forceinline__ float bf2f(ushort u) {
    return __uint_as_float(((uint)u) << 16);
}

// ---------------------------------------------------------------------------
// Prep: pack A (19 tiles) and C (16 tiles) into MFMA fragment order, bf16 hi/lo.
// Layout (ushort): Af_h[19][10][64][8] | Af_l | Cf_h[16][10][64][8] | Cf_l
// Fragment mapping (16x16x32): elem (m, k) -> lane = (k>>3)*16 + m, reg = k&7.
// ---------------------------------------------------------------------------
__global__ void prep_kernel(const float* __restrict__ A, const float* __restrict__ C,
                            ushort* __restrict__ ws) {
    const int it   = blockIdx.x;          // 0..34
    const int ks   = blockIdx.y;          // 0..9
    const int lane = threadIdx.x;         // 0..63
    const bool isA = (it < NT_A);
    const float* __restrict__ W = isA ? A : C;
    const int M   = isA ? STATE : 256;
    const int itl = isA ? it : it - NT_A;
    const int row = itl*16 + (lane & 15);
    const int k0  = ks*32 + (lane >> 4)*8;

    ushort hv[8], lv[8];
    #pragma unroll
    for (int j = 0; j < 8; ++j) {
        const int k = k0 + j;
        float v = 0.f;
        if (row < M && k < STATE) v = W[row*STATE + k];
        const ushort h = f2bf(v);
        hv[j] = h;
        lv[j] = f2bf(v - bf2f(h));
    }
    const int plane = (isA ? NT_A : NT_C)*10*64*8;
    ushort* hb = ws + (isA ? 0 : 2*NT_A*10*64*8) + ((itl*10 + ks)*64 + lane)*8;
    ushort* lb = hb + plane;
    #pragma unroll
    for (int j = 0; j < 8; ++j) { hb[j] = hv[j]; lb[j] = lv[j]; }
}

// ---------------------------------------------------------------------------
// Main: per (b,p) block, 512 threads (8 waves), 1 block/CU (83.2 KB LDS).
// LDS: Xs[h][t'][k] bf16, t' = 0 -> x0, t' >= 1 -> X[..., t'-1]; XOR-swizzled.
// pred B-frag cols t' = tt*16+c ; recon B-frag cols t' = tt*16+c+1.
// 3-pass MFMA: Wh@Xh + Wh@Xl + Wl@Xh.
// ---------------------------------------------------------------------------
#define DO_TT(ACC, TT_, PHOFF) { \
    const int tp  = (TT_)*16 + c + (PHOFF); \
    const int off = (tp*ROWB + kbyte) ^ ((tp & 7) << 4); \
    const s16x8 bh = *(const s16x8*)(Xs + off); \
    const s16x8 bl = *(const s16x8*)(Xs + off + LDS_HALF); \
    ACC = __builtin_amdgcn_mfma_f32_16x16x32_bf16(ah, bh, ACC, 0, 0, 0); \
    ACC = __builtin_amdgcn_mfma_f32_16x16x32_bf16(ah, bl, ACC, 0, 0, 0); \
    ACC = __builtin_amdgcn_mfma_f32_16x16x32_bf16(al, bh, ACC, 0, 0, 0); \
}

__global__ __launch_bounds__(512, 1)
void pred_recon_mfma(const float* __restrict__ X, const float* __restrict__ x0,
                     const ushort* __restrict__ ws,
                     float* __restrict__ vid, float* __restrict__ Xpred) {
    __shared__ __align__(16) char Xs[2*LDS_HALF];   // 83200 B
    const int bp   = blockIdx.x;
    const int tid  = threadIdx.x;
    const int lane = tid & 63;
    const int w    = tid >> 6;                      // 0..7

    // ---- stage X -> LDS (transposed, bf16 hi/lo, swizzled) -----------------
    const float* __restrict__ Xbp = X + (size_t)bp*(STATE*TDIM);
    #pragma unroll 1
    for (int i = 0; i < 10; ++i) {
        const int k4 = w + 8*i;
        if (k4 < 75) {
            const int k = k4*4;
            const int t = lane;
            const float v0 = Xbp[(k+0)*TDIM + t];
            const float v1 = Xbp[(k+1)*TDIM + t];
            const float v2 = Xbp[(k+2)*TDIM + t];
            const float v3 = Xbp[(k+3)*TDIM + t];
            const ushort h0 = f2bf(v0), h1 = f2bf(v1), h2 = f2bf(v2), h3 = f2bf(v3);
            uint2 hp, lp;
            hp.x = (uint)h0 | ((uint)h1 << 16);
            hp.y = (uint)h2 | ((uint)h3 << 16);
            lp.x = (uint)f2bf(v0 - bf2f(h0)) | ((uint)f2bf(v1 - bf2f(h1)) << 16);
            lp.y = (uint)f2bf(v2 - bf2f(h2)) | ((uint)f2bf(v3 - bf2f(h3)) << 16);
            const int tp  = t + 1;
            const int off = (tp*ROWB + k*2) ^ ((tp & 7) << 4);
            *(uint2*)(Xs + off)            = hp;
            *(uint2*)(Xs + off + LDS_HALF) = lp;
        }
    }
    const float* __restrict__ x0bp = x0 + (size_t)bp*STATE;
    for (int k = tid; k < STATE; k += 512) {        // t' = 0 row (swz = 0)
        const float v = x0bp[k];
        const ushort h = f2bf(v);
        *(ushort*)(Xs + k*2)            = h;
        *(ushort*)(Xs + k*2 + LDS_HALF) = f2bf(v - bf2f(h));
    }
    for (int idx = tid; idx < 130; idx += 512) {    // zero pad k = 300..319
        const int h = idx / 65, tp = idx % 65;
        char* base = Xs + h*LDS_HALF;
        const int sw = (tp & 7) << 4;
        uint2 z; z.x = 0u; z.y = 0u;
        #pragma unroll
        for (int j = 0; j < 5; ++j)
            *(uint2*)(base + ((tp*ROWB + 600 + j*8) ^ sw)) = z;
    }
    __syncthreads();

    const int c  = lane & 15;
    const int kg = lane >> 4;
    const ushort* __restrict__ Af_h = ws;
    const ushort* __restrict__ Af_l = Af_h + NT_A*10*64*8;
    const ushort* __restrict__ Cf_h = Af_l + NT_A*10*64*8;
    const ushort* __restrict__ Cf_l = Cf_h + NT_C*10*64*8;

    // ------------------------- phase 0: X_pred ------------------------------
    {
        float* __restrict__ outp = Xpred + (size_t)bp*(STATE*TDIM);
        #pragma unroll 1
        for (int it = w; it < NT_A; it += 8) {
            f32x4 a0 = {0,0,0,0}, a1 = {0,0,0,0}, a2 = {0,0,0,0}, a3 = {0,0,0,0};
            #pragma unroll 2
            for (int ks = 0; ks < 10; ++ks) {
                const int kbyte = ks*64 + kg*16;
                const s16x8 ah = *(const s16x8*)(Af_h + ((it*10 + ks)*64 + lane)*8);
                const s16x8 al = *(const s16x8*)(Af_l + ((it*10 + ks)*64 + lane)*8);
                DO_TT(a0, 0, 0) DO_TT(a1, 1, 0) DO_TT(a2, 2, 0) DO_TT(a3, 3, 0)
            }
            #pragma unroll
            for (int r = 0; r < 4; ++r) {
                const int row = it*16 + kg*4 + r;
                if (row < STATE) {
                    outp[row*TDIM +  0 + c] = a0[r];
                    outp[row*TDIM + 16 + c] = a1[r];
                    outp[row*TDIM + 32 + c] = a2[r];
                    outp[row*TDIM + 48 + c] = a3[r];
                }
            }
        }
    }

    // ------------------------- phase 1: recon -> vid ------------------------
    {
        const int b = bp >> 2, p = bp & 3, gr = p >> 1, gc = p & 1;
        float* __restrict__ vb = vid + (size_t)b*(32*32*TDIM)
                                     + (size_t)(gr*16)*(32*TDIM)
                                     + (size_t)(gc*16)*TDIM;
        #pragma unroll 1
        for (int it = w; it < NT_C; it += 8) {
            f32x4 a0 = {0,0,0,0}, a1 = {0,0,0,0}, a2 = {0,0,0,0}, a3 = {0,0,0,0};
            #pragma unroll 2
            for (int ks = 0; ks < 10; ++ks) {
                const int kbyte = ks*64 + kg*16;
                const s16x8 ah = *(const s16x8*)(Cf_h + ((it*10 + ks)*64 + lane)*8);
                const s16x8 al = *(const s16x8*)(Cf_l + ((it*10 + ks)*64 + lane)*8);
                DO_TT(a0, 0, 1) DO_TT(a1, 1, 1) DO_TT(a2, 2, 1) DO_TT(a3, 3, 1)
            }
            #pragma unroll
            for (int r = 0; r < 4; ++r) {
                const int pc = kg*4 + r;           // i & 15  (patch x)
                float* vr = vb + it*(32*TDIM) + pc*TDIM;   // pr = it (patch y)
                vr[ 0 + c] = a0[r];
                vr[16 + c] = a1[r];
                vr[32 + c] = a2[r];
                vr[48 + c] = a3[r];
            }
        }
    }
}

// ---------------------------------------------------------------------------
// xu: X_U = 0.1*(1+exp(-Bm@U)) * sum_p |X|.  Grid (5 sgroups, 256 b).
// Phase 1: U in VGPRs, Bm rows via uniform (SMEM) loads -> no lgkm mixing.
// Phase 2: float4-coalesced streaming of X / XU via LDS-held gamma.
// ---------------------------------------------------------------------------
__global__ __launch_bounds__(256)
void xu_kernel(const float* __restrict__ X, const float* __restrict__ U,
               const float* __restrict__ Bm, float* __restrict__ XU) {
    __shared__ float gl[60*68];
    const int b    = blockIdx.y;
    const int sg   = blockIdx.x;              // 0..4
    const int tid  = threadIdx.x;
    const int lane = tid & 63;
    const int w    = __builtin_amdgcn_readfirstlane(tid >> 6);

    const float* __restrict__ Ub = U + (size_t)b*(NCAUSE*TDIM);
    float u[40];
    #pragma unroll
    for (int k = 0; k < 40; ++k) u[k] = Ub[k*TDIM + lane];

    const int sbase = sg*60;
    const int s0    = w*15;
    #pragma unroll 1
    for (int r = 0; r < 15; ++r) {
        const float* __restrict__ brow = Bm + (size_t)(sbase + s0 + r)*NCAUSE;
        float bu = 0.f;
        #pragma unroll
        for (int q = 0; q < 10; ++q) {
            const float4 m = *(const float4*)(brow + q*4);
            bu += m.x*u[4*q] + m.y*u[4*q+1] + m.z*u[4*q+2] + m.w*u[4*q+3];
        }
        gl[(s0 + r)*68 + lane] = 0.1f*(1.f + __expf(-bu));
    }
    __syncthreads();

    const float* __restrict__ Xb  = X  + (size_t)b*(NP*STATE*TDIM);
    float* __restrict__ XUb       = XU + (size_t)b*(STATE*TDIM);
    #pragma unroll 1
    for (int idx = tid; idx < 60*16; idx += 256) {
        const int sp = idx >> 4, t4 = idx & 15;
        const int s  = sbase + sp;
        const float4 g = *(const float4*)(gl + sp*68 + t4*4);
        float4 a; a.x = 0.f; a.y = 0.f; a.z = 0.f; a.w = 0.f;
        #pragma unroll
        for (int p = 0; p < NP; ++p) {
            const float4 xv = *(const float4*)(Xb + ((size_t)p*STATE + s)*TDIM + t4*4);
            a.x += fabsf(xv.x); a.y += fabsf(xv.y); a.z += fabsf(xv.z); a.w += fabsf(xv.w);
        }
        float4 o; o.x = g.x*a.x; o.y = g.y*a.y; o.z = g.z*a.z; o.w = g.w*a.w;
        *(float4*)(XUb + (size_t)s*TDIM + t4*4) = o;
    }
}

// ---------------------------------------------------------------------------
// Fallback (ws too small): round-1 fp32 kernel — correct, slower.
// ---------------------------------------------------------------------------
__global__ __launch_bounds__(256, 2)
void pred_recon_f32(const float* __restrict__ X, const float* __restrict__ x0,
                    const float* __restrict__ A, const float* __restrict__ C,
                    float* __restrict__ vid, float* __restrict__ Xpred) {
    __shared__ float Xsf[STATE*65];
    const int bp = blockIdx.x, tid = threadIdx.x;
    const float* Xbp = X + (size_t)bp*(STATE*TDIM);
    const float* x0bp = x0 + (size_t)bp*STATE;
    for (int idx = tid; idx < STATE*65; idx += 256) {
        const int k = idx/65, tp = idx - k*65;
        Xsf[idx] = (tp == 0) ? x0bp[k] : Xbp[k*TDIM + (tp-1)];
    }
    __syncthreads();
    const int t = tid & 63, rg = tid >> 6;
    float* outp = Xpred + (size_t)bp*(STATE*TDIM);
    for (int chunk = 0; chunk < 15; ++chunk) {
        const int i0 = rg*75 + chunk*5;
        float acc[5] = {0,0,0,0,0};
        for (int k4 = 0; k4 < STATE/4; ++k4) {
            const int kb = k4*4;
            const float x0v = Xsf[(kb+0)*65 + t], x1v = Xsf[(kb+1)*65 + t];
            const float x2v = Xsf[(kb+2)*65 + t], x3v = Xsf[(kb+3)*65 + t];
            #pragma unroll
            for (int r = 0; r < 5; ++r) {
                const float4 a = *(const float4*)(A + (size_t)(i0+r)*STATE + kb);
                acc[r] += a.x*x0v + a.y*x1v + a.z*x2v + a.w*x3v;
            }
        }
        #pragma unroll
        for (int r = 0; r < 5; ++r) outp[(i0+r)*TDIM + t] = acc[r];
    }
    const int b = bp >> 2, p = bp & 3, gr = p >> 1, gc = p & 1;
    float* vb = vid + (size_t)b*(32*32*TDIM) + (size_t)(gr*16)*(32*TDIM) + (size_t)(gc*16)*TDIM;
    for (int chunk = 0; chunk < 16; ++chunk) {
        const int i0 = rg*64 + chunk*4;
        float acc[4] = {0,0,0,0};
        for (int k4 = 0; k4 < STATE/4; ++k4) {
            const int kb = k4*4;
            const float x0v = Xsf[(kb+0)*65 + (t+1)], x1v = Xsf[(kb+1)*65 + (t+1)];
            const float x2v = Xsf[(kb+2)*65 + (t+1)], x3v = Xsf[(kb+3)*65 + (t+1)];
            #pragma unroll
            for (int r = 0; r < 4; ++r) {
                const float4 cc = *(const float4*)(C + (size_t)(i0+r)*STATE + kb);
                acc[r] += cc.x*x0v + cc.y*x1v + cc.z*x2v + cc.w*x3v;
            }
        }
        #pragma unroll
        for (int r = 0; r < 4; ++r) {
            const int i = i0 + r;
            vb[(i >> 4)*(32*TDIM) + (i & 15)*TDIM + t] = acc[r];
        }
    }
}

extern "C" void kernel_launch(void* const* d_in, const int* in_sizes, int n_in,
                              void* d_out, int out_size, void* d_ws, size_t ws_size,
                              hipStream_t stream) {
    const float* X  = (const float*)d_in[0];   // (256,4,300,1,64)
    const float* U  = (const float*)d_in[1];   // (256,1,40,1,64)
    const float* x0 = (const float*)d_in[2];   // (256,4,300,1)
    const float* A  = (const float*)d_in[3];   // (300,300)
    const float* Bm = (const float*)d_in[4];   // (300,40)
    const float* C  = (const float*)d_in[5];   // (256,300)

    float* out   = (float*)d_out;
    float* vid   = out;                        // 256*32*32*64  = 16777216
    float* Xpred = out + 16777216;             // 256*4*300*64  = 19660800
    float* XU    = out + 16777216 + 19660800;  // 256*300*64    =  4915200

    if (ws_size >= WS_NEEDED) {
        ushort* wsu = (ushort*)d_ws;
        hipLaunchKernelGGL(prep_kernel, dim3(NT_A + NT_C, 10), dim3(64), 0, stream,
                           A, C, wsu);
        hipLaunchKernelGGL(pred_recon_mfma, dim3(256*NP), dim3(512), 0, stream,
                           X, x0, wsu, vid, Xpred);
    } else {
        hipLaunchKernelGGL(pred_recon_f32, dim3(256*NP), dim3(256), 0, stream,
                           X, x0, A, C, vid, Xpred);
    }
    hipLaunchKernelGGL(xu_kernel, dim3(5, 256), dim3(256), 0, stream,
                       X, U, Bm, XU);
}

// Round 8
// 317.296 us; speedup vs baseline: 5.3924x; 1.0784x over previous
//
#include <hip/hip_runtime.h>

#define STATE  300
#define TDIM   64
#define NCAUSE 40
#define NP     4
#define KPAD   320
#define ROWB   (KPAD*2)          // 640 B LDS row; 640 % 128 == 0 -> XOR swizzle closed
#define NROWS  33                // t' rows per block (t-half + boundary)
#define LDS_HALF (NROWS*ROWB)    // 21120 B per hi/lo plane; total 42240 B -> 3 blocks/CU
#define NT_A   19
#define NT_C   16
#define WS_NEEDED 716800u

typedef float f32x4 __attribute__((ext_vector_type(4)));
typedef short s16x8 __attribute__((ext_vector_type(8)));

static __device__ __forceinline__ ushort f2bf(float f) {   // RNE f32 -> bf16 bits
    uint x = __float_as_uint(f);
    x += 0x7fffu + ((x >> 16) & 1u);
    return (ushort)(x >> 16);
}
static __device__ __forceinline__ float bf2f(ushort u) {
    return __uint_as_float(((uint)u) << 16);
}

// ---------------------------------------------------------------------------
// Prep: pack A (19 tiles) and C (16 tiles) into MFMA fragment order, bf16 hi/lo.
// Layout (ushort): Af_h[19][10][64][8] | Af_l | Cf_h[16][10][64][8] | Cf_l
// Fragment mapping (16x16x32): elem (m, k) -> lane = (k>>3)*16 + m, reg = k&7.
// ---------------------------------------------------------------------------
__global__ void prep_kernel(const float* __restrict__ A, const float* __restrict__ C,
                            ushort* __restrict__ ws) {
    const int it   = blockIdx.x;          // 0..34
    const int ks   = blockIdx.y;          // 0..9
    const int lane = threadIdx.x;         // 0..63
    const bool isA = (it < NT_A);
    const float* __restrict__ W = isA ? A : C;
    const int M   = isA ? STATE : 256;
    const int itl = isA ? it : it - NT_A;
    const int row = itl*16 + (lane & 15);
    const int k0  = ks*32 + (lane >> 4)*8;

    ushort hv[8], lv[8];
    #pragma unroll
    for (int j = 0; j < 8; ++j) {
        const int k = k0 + j;
        float v = 0.f;
        if (row < M && k < STATE) v = W[row*STATE + k];
        const ushort h = f2bf(v);
        hv[j] = h;
        lv[j] = f2bf(v - bf2f(h));
    }
    const int plane = (isA ? NT_A : NT_C)*10*64*8;
    ushort* hb = ws + (isA ? 0 : 2*NT_A*10*64*8) + ((itl*10 + ks)*64 + lane)*8;
    ushort* lb = hb + plane;
    #pragma unroll
    for (int j = 0; j < 8; ++j) { hb[j] = hv[j]; lb[j] = lv[j]; }
}

#define MFMA_(A_,B_,C_) __builtin_amdgcn_mfma_f32_16x16x32_bf16((A_),(B_),(C_),0,0,0)

static __device__ __forceinline__ s16x8 ldA(const ushort* __restrict__ base, int it, int ks, int lane) {
    return *(const s16x8*)(base + ((it*10 + ks)*64 + lane)*8);
}
static __device__ __forceinline__ void ldB(const char* Xs, int lr, int kbyte, s16x8& bh, s16x8& bl) {
    const int off = (lr*ROWB + kbyte) ^ ((lr & 7) << 4);
    bh = *(const s16x8*)(Xs + off);
    bl = *(const s16x8*)(Xs + off + LDS_HALF);
}

// 2 output tiles x 2 t-subtiles, shared B reads; 12 MFMA per ks.
template<int PHOFF>
static __device__ __forceinline__ void gemm2(const char* Xs,
        const ushort* __restrict__ Wh, const ushort* __restrict__ Wl,
        int it0, int it1, int lane, int kg, int c,
        f32x4& a00, f32x4& a01, f32x4& a10, f32x4& a11) {
    #pragma unroll 2
    for (int ks = 0; ks < 10; ++ks) {
        const s16x8 ah0 = ldA(Wh, it0, ks, lane);
        const s16x8 al0 = ldA(Wl, it0, ks, lane);
        const s16x8 ah1 = ldA(Wh, it1, ks, lane);
        const s16x8 al1 = ldA(Wl, it1, ks, lane);
        const int kbyte = ks*64 + kg*16;
        s16x8 bh0, bl0, bh1, bl1;
        ldB(Xs, c + PHOFF,      kbyte, bh0, bl0);
        ldB(Xs, 16 + c + PHOFF, kbyte, bh1, bl1);
        a00 = MFMA_(ah0, bh0, a00); a00 = MFMA_(ah0, bl0, a00); a00 = MFMA_(al0, bh0, a00);
        a01 = MFMA_(ah0, bh1, a01); a01 = MFMA_(ah0, bl1, a01); a01 = MFMA_(al0, bh1, a01);
        a10 = MFMA_(ah1, bh0, a10); a10 = MFMA_(ah1, bl0, a10); a10 = MFMA_(al1, bh0, a10);
        a11 = MFMA_(ah1, bh1, a11); a11 = MFMA_(ah1, bl1, a11); a11 = MFMA_(al1, bh1, a11);
    }
}

template<int PHOFF>
static __device__ __forceinline__ void gemm1(const char* Xs,
        const ushort* __restrict__ Wh, const ushort* __restrict__ Wl,
        int it0, int lane, int kg, int c, f32x4& a00, f32x4& a01) {
    #pragma unroll 2
    for (int ks = 0; ks < 10; ++ks) {
        const s16x8 ah0 = ldA(Wh, it0, ks, lane);
        const s16x8 al0 = ldA(Wl, it0, ks, lane);
        const int kbyte = ks*64 + kg*16;
        s16x8 bh0, bl0, bh1, bl1;
        ldB(Xs, c + PHOFF,      kbyte, bh0, bl0);
        ldB(Xs, 16 + c + PHOFF, kbyte, bh1, bl1);
        a00 = MFMA_(ah0, bh0, a00); a00 = MFMA_(ah0, bl0, a00); a00 = MFMA_(al0, bh0, a00);
        a01 = MFMA_(ah0, bh1, a01); a01 = MFMA_(ah0, bl1, a01); a01 = MFMA_(al0, bh1, a01);
    }
}

// ---------------------------------------------------------------------------
// Main: per (bp, t-half) block, 256 threads (4 waves), 3 blocks/CU.
// LDS rows lr = 0..32 <-> t' = th*32 + lr (row 32/0 shared at the seam).
// Wave tile split: w0 pred 0-8, w1 pred 9-17, w2 pred 18 + recon 0-7,
//                  w3 recon 8-15  (540/540/540/480 MFMA — balanced).
// ---------------------------------------------------------------------------
__global__ __launch_bounds__(256, 3)
void pred_recon_mfma(const float* __restrict__ X, const float* __restrict__ x0,
                     const ushort* __restrict__ ws,
                     float* __restrict__ vid, float* __restrict__ Xpred) {
    __shared__ __align__(16) char Xs[2*LDS_HALF];   // 42240 B
    const int bp   = blockIdx.x;
    const int th   = blockIdx.y;                    // t-half: 0 or 1
    const int tid  = threadIdx.x;
    const int lane = tid & 63;
    const int w    = tid >> 6;                      // 0..3

    // ---- stage X -> LDS (transposed, bf16 hi/lo, swizzled) -----------------
    const float* __restrict__ Xbp = X + (size_t)bp*(STATE*TDIM);
    {
        const int t_lo = tid & 31;                  // 0..31
        const int kh   = tid >> 5;                  // 0..7
        const int tg   = th*32 + t_lo;
        const int lr   = t_lo + 1;
        const int sw   = (lr & 7) << 4;
        #pragma unroll 1
        for (int i = 0; i < 10; ++i) {
            const int k4 = kh + 8*i;
            if (k4 < 75) {
                const int k = k4*4;
                const float v0 = Xbp[(k+0)*TDIM + tg];
                const float v1 = Xbp[(k+1)*TDIM + tg];
                const float v2 = Xbp[(k+2)*TDIM + tg];
                const float v3 = Xbp[(k+3)*TDIM + tg];
                const ushort h0 = f2bf(v0), h1 = f2bf(v1), h2 = f2bf(v2), h3 = f2bf(v3);
                uint2 hp, lp;
                hp.x = (uint)h0 | ((uint)h1 << 16);
                hp.y = (uint)h2 | ((uint)h3 << 16);
                lp.x = (uint)f2bf(v0 - bf2f(h0)) | ((uint)f2bf(v1 - bf2f(h1)) << 16);
                lp.y = (uint)f2bf(v2 - bf2f(h2)) | ((uint)f2bf(v3 - bf2f(h3)) << 16);
                const int off = (lr*ROWB + k*2) ^ sw;
                *(uint2*)(Xs + off)            = hp;
                *(uint2*)(Xs + off + LDS_HALF) = lp;
            }
        }
    }
    // lr = 0 row: th0 -> x0;  th1 -> X[..., t=31]   (swizzle term is 0)
    if (th == 0) {
        const float* __restrict__ x0bp = x0 + (size_t)bp*STATE;
        for (int k = tid; k < STATE; k += 256) {
            const float v = x0bp[k];
            const ushort h = f2bf(v);
            *(ushort*)(Xs + k*2)            = h;
            *(ushort*)(Xs + k*2 + LDS_HALF) = f2bf(v - bf2f(h));
        }
    } else {
        for (int k = tid; k < STATE; k += 256) {
            const float v = Xbp[k*TDIM + 31];
            const ushort h = f2bf(v);
            *(ushort*)(Xs + k*2)            = h;
            *(ushort*)(Xs + k*2 + LDS_HALF) = f2bf(v - bf2f(h));
        }
    }
    // zero pad k = 300..319 for all rows, both planes
    for (int idx = tid; idx < 2*NROWS; idx += 256) {
        const int plane = idx & 1, lr = idx >> 1;
        char* base = Xs + plane*LDS_HALF;
        const int sw = (lr & 7) << 4;
        uint2 z; z.x = 0u; z.y = 0u;
        #pragma unroll
        for (int j = 0; j < 5; ++j)
            *(uint2*)(base + ((lr*ROWB + 600 + j*8) ^ sw)) = z;
    }
    __syncthreads();

    const int c  = lane & 15;
    const int kg = lane >> 4;
    const int tbase = th*32;
    const ushort* __restrict__ Af_h = ws;
    const ushort* __restrict__ Af_l = Af_h + NT_A*10*64*8;
    const ushort* __restrict__ Cf_h = Af_l + NT_A*10*64*8;
    const ushort* __restrict__ Cf_l = Cf_h + NT_C*10*64*8;

    // per-wave work ranges (see header comment)
    const int ps = (w*9 < NT_A) ? w*9 : NT_A;
    const int pe = (ps + 9 < NT_A) ? ps + 9 : NT_A;
    const int rs = (w < 3) ? 0 : 8;
    const int re = (w < 2) ? 0 : (w - 1)*8;

    // ------------------------- pred: X_pred ---------------------------------
    {
        float* __restrict__ outp = Xpred + (size_t)bp*(STATE*TDIM);
        int it = ps;
        for (; it + 1 < pe; it += 2) {
            f32x4 a00 = {0,0,0,0}, a01 = {0,0,0,0}, a10 = {0,0,0,0}, a11 = {0,0,0,0};
            gemm2<0>(Xs, Af_h, Af_l, it, it+1, lane, kg, c, a00, a01, a10, a11);
            #pragma unroll
            for (int r = 0; r < 4; ++r) {
                const int row0 = it*16 + kg*4 + r;
                const int row1 = row0 + 16;
                outp[row0*TDIM + tbase + c]      = a00[r];
                outp[row0*TDIM + tbase + 16 + c] = a01[r];
                if (row1 < STATE) {
                    outp[row1*TDIM + tbase + c]      = a10[r];
                    outp[row1*TDIM + tbase + 16 + c] = a11[r];
                }
            }
        }
        if (it < pe) {
            f32x4 a00 = {0,0,0,0}, a01 = {0,0,0,0};
            gemm1<0>(Xs, Af_h, Af_l, it, lane, kg, c, a00, a01);
            #pragma unroll
            for (int r = 0; r < 4; ++r) {
                const int row = it*16 + kg*4 + r;
                if (row < STATE) {
                    outp[row*TDIM + tbase + c]      = a00[r];
                    outp[row*TDIM + tbase + 16 + c] = a01[r];
                }
            }
        }
    }

    // ------------------------- recon -> vid ---------------------------------
    if (rs < re) {
        const int b = bp >> 2, p = bp & 3, gr = p >> 1, gc = p & 1;
        float* __restrict__ vb = vid + (size_t)b*(32*32*TDIM)
                                     + (size_t)(gr*16)*(32*TDIM)
                                     + (size_t)(gc*16)*TDIM;
        for (int it = rs; it + 1 < re + 1; it += 2) {   // re-rs is even (4 pairs)
            f32x4 a00 = {0,0,0,0}, a01 = {0,0,0,0}, a10 = {0,0,0,0}, a11 = {0,0,0,0};
            gemm2<1>(Xs, Cf_h, Cf_l, it, it+1, lane, kg, c, a00, a01, a10, a11);
            #pragma unroll
            for (int r = 0; r < 4; ++r) {
                const int pc = kg*4 + r;
                float* vr0 = vb + (it  )*(32*TDIM) + pc*TDIM + tbase;
                float* vr1 = vb + (it+1)*(32*TDIM) + pc*TDIM + tbase;
                vr0[c]      = a00[r];
                vr0[16 + c] = a01[r];
                vr1[c]      = a10[r];
                vr1[16 + c] = a11[r];
            }
        }
    }
}

// ---------------------------------------------------------------------------
// xu: X_U = 0.1*(1+exp(-Bm@U)) * sum_p |X|.  Grid (5 sgroups, 256 b).
// ---------------------------------------------------------------------------
__global__ __launch_bounds__(256)
void xu_kernel(const float* __restrict__ X, const float* __restrict__ U,
               const float* __restrict__ Bm, float* __restrict__ XU) {
    __shared__ float gl[60*68];
    const int b    = blockIdx.y;
    const int sg   = blockIdx.x;              // 0..4
    const int tid  = threadIdx.x;
    const int lane = tid & 63;
    const int w    = __builtin_amdgcn_readfirstlane(tid >> 6);

    const float* __restrict__ Ub = U + (size_t)b*(NCAUSE*TDIM);
    float u[40];
    #pragma unroll
    for (int k = 0; k < 40; ++k) u[k] = Ub[k*TDIM + lane];

    const int sbase = sg*60;
    const int s0    = w*15;
    #pragma unroll 1
    for (int r = 0; r < 15; ++r) {
        const float* __restrict__ brow = Bm + (size_t)(sbase + s0 + r)*NCAUSE;
        float bu = 0.f;
        #pragma unroll
        for (int q = 0; q < 10; ++q) {
            const float4 m = *(const float4*)(brow + q*4);
            bu += m.x*u[4*q] + m.y*u[4*q+1] + m.z*u[4*q+2] + m.w*u[4*q+3];
        }
        gl[(s0 + r)*68 + lane] = 0.1f*(1.f + __expf(-bu));
    }
    __syncthreads();

    const float* __restrict__ Xb  = X  + (size_t)b*(NP*STATE*TDIM);
    float* __restrict__ XUb       = XU + (size_t)b*(STATE*TDIM);
    #pragma unroll 1
    for (int idx = tid; idx < 60*16; idx += 256) {
        const int sp = idx >> 4, t4 = idx & 15;
        const int s  = sbase + sp;
        const float4 g = *(const float4*)(gl + sp*68 + t4*4);
        float4 a; a.x = 0.f; a.y = 0.f; a.z = 0.f; a.w = 0.f;
        #pragma unroll
        for (int p = 0; p < NP; ++p) {
            const float4 xv = *(const float4*)(Xb + ((size_t)p*STATE + s)*TDIM + t4*4);
            a.x += fabsf(xv.x); a.y += fabsf(xv.y); a.z += fabsf(xv.z); a.w += fabsf(xv.w);
        }
        float4 o; o.x = g.x*a.x; o.y = g.y*a.y; o.z = g.z*a.z; o.w = g.w*a.w;
        *(float4*)(XUb + (size_t)s*TDIM + t4*4) = o;
    }
}

// ---------------------------------------------------------------------------
// Fallback (ws too small): fp32 kernel — correct, slower.
// ---------------------------------------------------------------------------
__global__ __launch_bounds__(256, 2)
void pred_recon_f32(const float* __restrict__ X, const float* __restrict__ x0,
                    const float* __restrict__ A, const float* __restrict__ C,
                    float* __restrict__ vid, float* __restrict__ Xpred) {
    __shared__ float Xsf[STATE*65];
    const int bp = blockIdx.x, tid = threadIdx.x;
    const float* Xbp = X + (size_t)bp*(STATE*TDIM);
    const float* x0bp = x0 + (size_t)bp*STATE;
    for (int idx = tid; idx < STATE*65; idx += 256) {
        const int k = idx/65, tp = idx - k*65;
        Xsf[idx] = (tp == 0) ? x0bp[k] : Xbp[k*TDIM + (tp-1)];
    }
    __syncthreads();
    const int t = tid & 63, rg = tid >> 6;
    float* outp = Xpred + (size_t)bp*(STATE*TDIM);
    for (int chunk = 0; chunk < 15; ++chunk) {
        const int i0 = rg*75 + chunk*5;
        float acc[5] = {0,0,0,0,0};
        for (int k4 = 0; k4 < STATE/4; ++k4) {
            const int kb = k4*4;
            const float x0v = Xsf[(kb+0)*65 + t], x1v = Xsf[(kb+1)*65 + t];
            const float x2v = Xsf[(kb+2)*65 + t], x3v = Xsf[(kb+3)*65 + t];
            #pragma unroll
            for (int r = 0; r < 5; ++r) {
                const float4 a = *(const float4*)(A + (size_t)(i0+r)*STATE + kb);
                acc[r] += a.x*x0v + a.y*x1v + a.z*x2v + a.w*x3v;
            }
        }
        #pragma unroll
        for (int r = 0; r < 5; ++r) outp[(i0+r)*TDIM + t] = acc[r];
    }
    const int b = bp >> 2, p = bp & 3, gr = p >> 1, gc = p & 1;
    float* vb = vid + (size_t)b*(32*32*TDIM) + (size_t)(gr*16)*(32*TDIM) + (size_t)(gc*16)*TDIM;
    for (int chunk = 0; chunk < 16; ++chunk) {
        const int i0 = rg*64 + chunk*4;
        float acc[4] = {0,0,0,0};
        for (int k4 = 0; k4 < STATE/4; ++k4) {
            const int kb = k4*4;
            const float x0v = Xsf[(kb+0)*65 + (t+1)], x1v = Xsf[(kb+1)*65 + (t+1)];
            const float x2v = Xsf[(kb+2)*65 + (t+1)], x3v = Xsf[(kb+3)*65 + (t+1)];
            #pragma unroll
            for (int r = 0; r < 4; ++r) {
                const float4 cc = *(const float4*)(C + (size_t)(i0+r)*STATE + kb);
                acc[r] += cc.x*x0v + cc.y*x1v + cc.z*x2v + cc.w*x3v;
            }
        }
        #pragma unroll
        for (int r = 0; r < 4; ++r) {
            const int i = i0 + r;
            vb[(i >> 4)*(32*TDIM) + (i & 15)*TDIM + t] = acc[r];
        }
    }
}

extern "C" void kernel_launch(void* const* d_in, const int* in_sizes, int n_in,
                              void* d_out, int out_size, void* d_ws, size_t ws_size,
                              hipStream_t stream) {
    const float* X  = (const float*)d_in[0];   // (256,4,300,1,64)
    const float* U  = (const float*)d_in[1];   // (256,1,40,1,64)
    const float* x0 = (const float*)d_in[2];   // (256,4,300,1)
    const float* A  = (const float*)d_in[3];   // (300,300)
    const float* Bm = (const float*)d_in[4];   // (300,40)
    const float* C  = (const float*)d_in[5];   // (256,300)

    float* out   = (float*)d_out;
    float* vid   = out;                        // 256*32*32*64  = 16777216
    float* Xpred = out + 16777216;             // 256*4*300*64  = 19660800
    float* XU    = out + 16777216 + 19660800;  // 256*300*64    =  4915200

    if (ws_size >= WS_NEEDED) {
        ushort* wsu = (ushort*)d_ws;
        hipLaunchKernelGGL(prep_kernel, dim3(NT_A + NT_C, 10), dim3(64), 0, stream,
                           A, C, wsu);
        hipLaunchKernelGGL(pred_recon_mfma, dim3(256*NP, 2), dim3(256), 0, stream,
                           X, x0, wsu, vid, Xpred);
    } else {
        hipLaunchKernelGGL(pred_recon_f32, dim3(256*NP), dim3(256), 0, stream,
                           X, x0, A, C, vid, Xpred);
    }
    hipLaunchKernelGGL(xu_kernel, dim3(5, 256), dim3(256), 0, stream,
                       X, U, Bm, XU);
}